// Round 2
// baseline (225.573 us; speedup 1.0000x reference)
//
#include <hip/hip_runtime.h>

#define BATCH 32768
#define SEQ 512
#define TPL 8          // timesteps per lane (64 lanes * 8 = 512)
#define EPS 1e-8f
#define ROWS 4         // rows per wave, software-pipelined 1-deep

// v4: multi-row software pipelining.
// Round-1 evidence: two different memory structures (LDS-staged vs scattered)
// both pin at 86us / 1.95 TB/s with VALUBusy<=25% -> latency-bound with a tiny
// per-wave load-issue duty cycle (each wave loads once, then computes ~5k cyc).
// Fix: each wave owns 4 consecutive rows and double-buffers them in registers:
// row k+1's 13 loads are in flight while row k runs its scan/replay. Also
// amortizes tanh(lambda)/gamma prep 4x (row-invariant, lane ownership fixed).

struct RowBuf {
    float  vj[TPL];      // values[row][1+t0 .. 1+t0+8)
    float4 ra, rb;       // rewards
    float4 da, db;       // dones
    float  vlast;        // values[row][SEQ]
};

__device__ __forceinline__ void load_row(const float* __restrict__ values,
                                         const float* __restrict__ rewards,
                                         const float* __restrict__ dones,
                                         int row, int t0, RowBuf& b) {
    const float* __restrict__ vrow = values  + (size_t)row * (SEQ + 1);
    const float* __restrict__ rrow = rewards + (size_t)row * SEQ + t0;
    const float* __restrict__ drow = dones   + (size_t)row * SEQ + t0;
    #pragma unroll
    for (int j = 0; j < TPL; ++j)
        b.vj[j] = vrow[1 + t0 + j];          // misaligned run -> scalar dwords
    b.ra = *(const float4*)(rrow);
    b.rb = *(const float4*)(rrow + 4);
    b.da = *(const float4*)(drow);
    b.db = *(const float4*)(drow + 4);
    b.vlast = vrow[SEQ];
}

__device__ __forceinline__ void compute_store(float* __restrict__ out,
                                              int row, int t0, int lane,
                                              const float gl[TPL],
                                              const float gl1[TPL],
                                              const RowBuf& bu) {
    const float rj[TPL] = {bu.ra.x, bu.ra.y, bu.ra.z, bu.ra.w,
                           bu.rb.x, bu.rb.y, bu.rb.z, bu.rb.w};
    const float dj[TPL] = {bu.da.x, bu.da.y, bu.da.z, bu.da.w,
                           bu.db.x, bu.db.y, bu.db.z, bu.db.w};

    // per-lane affine summary (t descending):
    // a_t = gamma*lam*(1-d), b_t = r + gamma*(1-lam)*(1-d)*v_{t+1}
    float a[TPL], b[TPL];
    float A = 1.f, Bv = 0.f;
    #pragma unroll
    for (int j = TPL - 1; j >= 0; --j) {
        const float e = 1.f - dj[j];
        a[j] = gl[j] * e;
        b[j] = fmaf(gl1[j] * e, bu.vj[j], rj[j]);
        Bv = fmaf(a[j], Bv, b[j]);
        A  = a[j] * A;
    }

    // wave-level inclusive suffix scan of (A,B)
    #pragma unroll
    for (int dlt = 1; dlt < 64; dlt <<= 1) {
        const float oA = __shfl_down(A, dlt, 64);
        const float oB = __shfl_down(Bv, dlt, 64);
        if (lane + dlt < 64) {                // compose(mine, downstream)
            Bv = fmaf(A, oB, Bv);
            A  = A * oA;
        }
    }
    float EA = __shfl_down(A, 1, 64);
    float EB = __shfl_down(Bv, 1, 64);
    if (lane == 63) { EA = 1.f; EB = 0.f; }

    float ret = fmaf(EA, bu.vlast, EB);       // boundary ret for this lane

    float o[TPL];
    #pragma unroll
    for (int j = TPL - 1; j >= 0; --j) {
        ret = fmaf(a[j], ret, b[j]);
        o[j] = ret;
    }
    float* __restrict__ orow = out + (size_t)row * SEQ + t0;
    *(float4*)(orow)     = make_float4(o[0], o[1], o[2], o[3]);
    *(float4*)(orow + 4) = make_float4(o[4], o[5], o[6], o[7]);
}

__global__ void __launch_bounds__(256)
glr_wave_scan4(const float* __restrict__ values,
               const float* __restrict__ rewards,
               const float* __restrict__ dones,
               const float* __restrict__ raw_gamma,
               const float* __restrict__ raw_lambd,
               float* __restrict__ out) {
    const int lane = threadIdx.x & 63;
    const int wv   = threadIdx.x >> 6;
    const int wave = blockIdx.x * 4 + wv;     // 0..8191
    const int row0 = wave * ROWS;             // 4 consecutive rows per wave
    const int t0   = lane * TPL;

    RowBuf A, B;
    load_row(values, rewards, dones, row0 + 0, t0, A);   // issue first

    // lambda/gamma prep runs while row0's loads are in flight (row-invariant,
    // computed once per wave instead of once per row)
    const float gamma = fmaxf(tanhf(raw_gamma[0]), EPS);
    const float4 l4a = *(const float4*)(raw_lambd + t0);
    const float4 l4b = *(const float4*)(raw_lambd + t0 + 4);
    const float lr[TPL] = {l4a.x, l4a.y, l4a.z, l4a.w,
                           l4b.x, l4b.y, l4b.z, l4b.w};
    float gl[TPL], gl1[TPL];
    #pragma unroll
    for (int j = 0; j < TPL; ++j) {
        const float lm = fmaxf(tanhf(lr[j]), EPS);
        gl[j]  = gamma * lm;          // a_t / (1-d)
        gl1[j] = gamma * (1.f - lm);  // (b_t - r_t) / ((1-d)*v)
    }

    // fully unrolled 1-deep pipeline, named buffers only (no runtime indexing)
    load_row(values, rewards, dones, row0 + 1, t0, B);
    compute_store(out, row0 + 0, t0, lane, gl, gl1, A);
    load_row(values, rewards, dones, row0 + 2, t0, A);
    compute_store(out, row0 + 1, t0, lane, gl, gl1, B);
    load_row(values, rewards, dones, row0 + 3, t0, B);
    compute_store(out, row0 + 2, t0, lane, gl, gl1, A);
    compute_store(out, row0 + 3, t0, lane, gl, gl1, B);
}

extern "C" void kernel_launch(void* const* d_in, const int* in_sizes, int n_in,
                              void* d_out, int out_size, void* d_ws, size_t ws_size,
                              hipStream_t stream) {
    const float* values    = (const float*)d_in[0];
    const float* rewards   = (const float*)d_in[1];
    const float* dones     = (const float*)d_in[2];
    const float* raw_gamma = (const float*)d_in[3];
    const float* raw_lambd = (const float*)d_in[4];
    float* out = (float*)d_out;

    const int block = 256;                    // 4 waves/block
    const int grid  = BATCH / (4 * ROWS);     // 2048 blocks
    glr_wave_scan4<<<grid, block, 0, stream>>>(
        values, rewards, dones, raw_gamma, raw_lambd, out);
}

// Round 4
// 218.387 us; speedup vs baseline: 1.0329x; 1.0329x over previous
//
#include <hip/hip_runtime.h>

#define BATCH 32768
#define SEQ 512
#define TPL 8          // timesteps per lane (64 lanes * 8 = 512)
#define EPS 1e-8f

typedef float floatx4 __attribute__((ext_vector_type(4)));  // clang-native vec
                                                            // (nontemporal builtin
                                                            // rejects HIP_vector_type)

// v5b = v3 + NON-TEMPORAL output stores. Single-variable A/B vs round 1.
//
// Evidence (r0-r2): v2/v3/v4 (LDS-staged / scattered / pipelined) all pin at
// 86-92us with identical hbm_bytes=168MB @ ~1.95 TB/s. Logical reads are
// 201.5MB but FETCH is only 99MB: inputs are half-resident in the 256MiB LLC
// across bench iterations. Working set 265.5MB > LLC because the 64MB/iter
// write-only `out` stream allocates in LLC and evicts inputs each iteration.
// Kernel time == HBM refill time of the evicted half. Fix: `nt` stores so
// `out` stops polluting LLC; inputs (201.5MB) then fit and stay resident.
__global__ void __launch_bounds__(256)
glr_wave_scan5(const float* __restrict__ values,
               const float* __restrict__ rewards,
               const float* __restrict__ dones,
               const float* __restrict__ raw_gamma,
               const float* __restrict__ raw_lambd,
               float* __restrict__ out) {
    const int lane = threadIdx.x & 63;
    const int wv   = threadIdx.x >> 6;
    const int row  = blockIdx.x * 4 + wv;
    const int t0   = lane * TPL;

    const float* __restrict__ vrow = values  + (size_t)row * (SEQ + 1);
    const float* __restrict__ rrow = rewards + (size_t)row * SEQ + t0;
    const float* __restrict__ drow = dones   + (size_t)row * SEQ + t0;
    float*       __restrict__ orow = out     + (size_t)row * SEQ + t0;

    // ---- issue ALL independent global loads up front ----
    float vj[TPL];
    #pragma unroll
    for (int j = 0; j < TPL; ++j)
        vj[j] = vrow[1 + t0 + j];            // misaligned run -> scalar dwords

    const float4 r4a = *(const float4*)(rrow);
    const float4 r4b = *(const float4*)(rrow + 4);
    const float4 d4a = *(const float4*)(drow);
    const float4 d4b = *(const float4*)(drow + 4);
    const float4 l4a = *(const float4*)(raw_lambd + t0);      // 32B-aligned
    const float4 l4b = *(const float4*)(raw_lambd + t0 + 4);
    const float vlast = vrow[SEQ];           // wave-uniform address (1 line)

    const float gamma = fmaxf(tanhf(raw_gamma[0]), EPS);

    float rj[TPL] = {r4a.x, r4a.y, r4a.z, r4a.w, r4b.x, r4b.y, r4b.z, r4b.w};
    float dj[TPL] = {d4a.x, d4a.y, d4a.z, d4a.w, d4b.x, d4b.y, d4b.z, d4b.w};
    const float lr[TPL] = {l4a.x, l4a.y, l4a.z, l4a.w, l4b.x, l4b.y, l4b.z, l4b.w};
    float lm[TPL];
    #pragma unroll
    for (int j = 0; j < TPL; ++j)
        lm[j] = fmaxf(tanhf(lr[j]), EPS);

    // ---- per-lane affine summary (t descending) ----
    float a[TPL], b[TPL];
    float A = 1.f, Bv = 0.f;
    #pragma unroll
    for (int j = TPL - 1; j >= 0; --j) {
        const float g = gamma * (1.f - dj[j]);
        a[j] = g * lm[j];
        b[j] = fmaf(g * (1.f - lm[j]), vj[j], rj[j]);
        Bv = fmaf(a[j], Bv, b[j]);
        A  = a[j] * A;
    }

    // ---- wave-level inclusive suffix scan of (A,B) ----
    #pragma unroll
    for (int dlt = 1; dlt < 64; dlt <<= 1) {
        const float oA = __shfl_down(A, dlt, 64);
        const float oB = __shfl_down(Bv, dlt, 64);
        if (lane + dlt < 64) {                // compose(mine, downstream)
            Bv = fmaf(A, oB, Bv);
            A  = A * oA;
        }
    }
    float EA = __shfl_down(A, 1, 64);
    float EB = __shfl_down(Bv, 1, 64);
    if (lane == 63) { EA = 1.f; EB = 0.f; }

    // ret at this lane's right boundary; values[row][SEQ] is the scan init
    float ret = fmaf(EA, vlast, EB);

    // ---- replay, emit outputs (non-temporal: out is never re-read) ----
    float o[TPL];
    #pragma unroll
    for (int j = TPL - 1; j >= 0; --j) {
        ret = fmaf(a[j], ret, b[j]);
        o[j] = ret;
    }
    floatx4 o0 = {o[0], o[1], o[2], o[3]};
    floatx4 o1 = {o[4], o[5], o[6], o[7]};
    __builtin_nontemporal_store(o0, (floatx4*)(orow));
    __builtin_nontemporal_store(o1, (floatx4*)(orow + 4));
}

extern "C" void kernel_launch(void* const* d_in, const int* in_sizes, int n_in,
                              void* d_out, int out_size, void* d_ws, size_t ws_size,
                              hipStream_t stream) {
    const float* values    = (const float*)d_in[0];
    const float* rewards   = (const float*)d_in[1];
    const float* dones     = (const float*)d_in[2];
    const float* raw_gamma = (const float*)d_in[3];
    const float* raw_lambd = (const float*)d_in[4];
    float* out = (float*)d_out;

    const int block = 256;                 // 4 waves = 4 rows per block
    const int grid = BATCH / 4;            // 8192 blocks
    glr_wave_scan5<<<grid, block, 0, stream>>>(
        values, rewards, dones, raw_gamma, raw_lambd, out);
}

// Round 5
// 217.773 us; speedup vs baseline: 1.0358x; 1.0028x over previous
//
#include <hip/hip_runtime.h>

#define BATCH 32768
#define SEQ 512
#define TPL 8          // timesteps per lane (64 lanes * 8 = 512)
#define EPS 1e-8f

// v6 = v3 with the values path fully vectorized. A/B vs v3 (r1): only change
// is HOW values[row][1..512] reaches registers; nt stores reverted (r4 showed
// they only add HBM write traffic).
//
// Evidence r0-r4: v2 (LDS), v3 (scattered scalar), v4 (pipelined), v5 (nt)
// all land 86-92us, FETCH byte-identical 98.9MB (eviction is the harness's
// output-poison memset, not our stores). Nothing on-chip is saturated
// (VALU 24%, HBM 25%, occ 70%). Last unexamined resource: per-CU L1/TA
// transaction rate. v3's 8 strided scalar values-loads = 16 line-segment
// transactions EACH (128/wave for 17 distinct lines). This vectorization cuts
// per-wave transactions 193 -> ~81:
//   vj[0..6] = elements of the ALIGNED float4 pair at vrow+t0 (2 dwordx4),
//   vj[7]    = vrow[t0+8] = next lane's first element -> one shfl_down;
//   lane 63 patches vj[7] with vlast (= vrow[512], needed anyway).
__global__ void __launch_bounds__(256)
glr_wave_scan6(const float* __restrict__ values,
               const float* __restrict__ rewards,
               const float* __restrict__ dones,
               const float* __restrict__ raw_gamma,
               const float* __restrict__ raw_lambd,
               float* __restrict__ out) {
    const int lane = threadIdx.x & 63;
    const int wv   = threadIdx.x >> 6;
    const int row  = blockIdx.x * 4 + wv;
    const int t0   = lane * TPL;

    const float* __restrict__ vrow = values  + (size_t)row * (SEQ + 1);
    const float* __restrict__ rrow = rewards + (size_t)row * SEQ + t0;
    const float* __restrict__ drow = dones   + (size_t)row * SEQ + t0;
    float*       __restrict__ orow = out     + (size_t)row * SEQ + t0;

    // ---- issue ALL independent global loads up front (all dwordx4) ----
    const float4 v4a = *(const float4*)(vrow + t0);       // vrow[t0..t0+3]
    const float4 v4b = *(const float4*)(vrow + t0 + 4);   // vrow[t0+4..t0+7]
    const float4 r4a = *(const float4*)(rrow);
    const float4 r4b = *(const float4*)(rrow + 4);
    const float4 d4a = *(const float4*)(drow);
    const float4 d4b = *(const float4*)(drow + 4);
    const float4 l4a = *(const float4*)(raw_lambd + t0);
    const float4 l4b = *(const float4*)(raw_lambd + t0 + 4);
    const float vlast = vrow[SEQ];        // wave-uniform -> scalarized load

    const float gamma = fmaxf(tanhf(raw_gamma[0]), EPS);

    // vj[j] = vrow[1 + t0 + j]: shift the aligned pair left by one element,
    // pulling element 8 from the next lane. Lane 63: vrow[512] == vlast.
    const float nx = __shfl_down(v4a.x, 1, 64);
    float vj[TPL] = {v4a.y, v4a.z, v4a.w, v4b.x, v4b.y, v4b.z, v4b.w,
                     (lane == 63) ? vlast : nx};

    float rj[TPL] = {r4a.x, r4a.y, r4a.z, r4a.w, r4b.x, r4b.y, r4b.z, r4b.w};
    float dj[TPL] = {d4a.x, d4a.y, d4a.z, d4a.w, d4b.x, d4b.y, d4b.z, d4b.w};
    const float lr[TPL] = {l4a.x, l4a.y, l4a.z, l4a.w, l4b.x, l4b.y, l4b.z, l4b.w};
    float lm[TPL];
    #pragma unroll
    for (int j = 0; j < TPL; ++j)
        lm[j] = fmaxf(tanhf(lr[j]), EPS);

    // ---- per-lane affine summary (t descending) ----
    float a[TPL], b[TPL];
    float A = 1.f, Bv = 0.f;
    #pragma unroll
    for (int j = TPL - 1; j >= 0; --j) {
        const float g = gamma * (1.f - dj[j]);
        a[j] = g * lm[j];
        b[j] = fmaf(g * (1.f - lm[j]), vj[j], rj[j]);
        Bv = fmaf(a[j], Bv, b[j]);
        A  = a[j] * A;
    }

    // ---- wave-level inclusive suffix scan of (A,B) ----
    #pragma unroll
    for (int dlt = 1; dlt < 64; dlt <<= 1) {
        const float oA = __shfl_down(A, dlt, 64);
        const float oB = __shfl_down(Bv, dlt, 64);
        if (lane + dlt < 64) {                // compose(mine, downstream)
            Bv = fmaf(A, oB, Bv);
            A  = A * oA;
        }
    }
    float EA = __shfl_down(A, 1, 64);
    float EB = __shfl_down(Bv, 1, 64);
    if (lane == 63) { EA = 1.f; EB = 0.f; }

    // ret at this lane's right boundary; values[row][SEQ] is the scan init
    float ret = fmaf(EA, vlast, EB);

    // ---- replay, emit outputs ----
    float o[TPL];
    #pragma unroll
    for (int j = TPL - 1; j >= 0; --j) {
        ret = fmaf(a[j], ret, b[j]);
        o[j] = ret;
    }
    *(float4*)(orow)     = make_float4(o[0], o[1], o[2], o[3]);
    *(float4*)(orow + 4) = make_float4(o[4], o[5], o[6], o[7]);
}

extern "C" void kernel_launch(void* const* d_in, const int* in_sizes, int n_in,
                              void* d_out, int out_size, void* d_ws, size_t ws_size,
                              hipStream_t stream) {
    const float* values    = (const float*)d_in[0];
    const float* rewards   = (const float*)d_in[1];
    const float* dones     = (const float*)d_in[2];
    const float* raw_gamma = (const float*)d_in[3];
    const float* raw_lambd = (const float*)d_in[4];
    float* out = (float*)d_out;

    const int block = 256;                 // 4 waves = 4 rows per block
    const int grid = BATCH / 4;            // 8192 blocks
    glr_wave_scan6<<<grid, block, 0, stream>>>(
        values, rewards, dones, raw_gamma, raw_lambd, out);
}

// Round 6
// 209.646 us; speedup vs baseline: 1.0760x; 1.0388x over previous
//
#include <hip/hip_runtime.h>

#define BATCH 32768
#define SEQ 512
#define TPL 8          // timesteps per lane (64 lanes * 8 = 512)
#define EPS 1e-8f

typedef float floatx4 __attribute__((ext_vector_type(4)));

// v7 = v6 + NON-TEMPORAL LOADS on `values` (residency control, single-variable).
//
// Evidence r0-r5: v2(LDS)/v3(scatter)/v4(pipeline)/v5(nt-store)/v6(vec) all
// land 86-92us with FETCH byte-identical at 98.9MB. Working set (values+r+d+out
// = 268.4MB) sits EXACTLY at LLC capacity (256MiB=268.4MB); cyclic traversal
// thrashes ~37% of reads as scattered-granule HBM misses served at ~2TB/s.
// Fix attempt: mark `values` evict-first (nt). values has zero cross-wave
// reuse (each 128B line belongs to one row / one wave). Then r+d+out (201MB)
// fit in LLC and stay resident; values streams sequentially (67MB/iter).
// Miss traffic: 99MB scattered -> 67MB streaming.
__global__ void __launch_bounds__(256)
glr_wave_scan7(const float* __restrict__ values,
               const float* __restrict__ rewards,
               const float* __restrict__ dones,
               const float* __restrict__ raw_gamma,
               const float* __restrict__ raw_lambd,
               float* __restrict__ out) {
    const int lane = threadIdx.x & 63;
    const int wv   = threadIdx.x >> 6;
    const int row  = blockIdx.x * 4 + wv;
    const int t0   = lane * TPL;

    const float* __restrict__ vrow = values  + (size_t)row * (SEQ + 1);
    const float* __restrict__ rrow = rewards + (size_t)row * SEQ + t0;
    const float* __restrict__ drow = dones   + (size_t)row * SEQ + t0;
    float*       __restrict__ orow = out     + (size_t)row * SEQ + t0;

    // ---- issue ALL independent global loads up front (all dwordx4) ----
    // values: non-temporal (evict-first) -> doesn't displace r/d/out in LLC
    const floatx4 v4a = __builtin_nontemporal_load((const floatx4*)(vrow + t0));
    const floatx4 v4b = __builtin_nontemporal_load((const floatx4*)(vrow + t0 + 4));
    const float4 r4a = *(const float4*)(rrow);
    const float4 r4b = *(const float4*)(rrow + 4);
    const float4 d4a = *(const float4*)(drow);
    const float4 d4b = *(const float4*)(drow + 4);
    const float4 l4a = *(const float4*)(raw_lambd + t0);
    const float4 l4b = *(const float4*)(raw_lambd + t0 + 4);
    const float vlast = __builtin_nontemporal_load(vrow + SEQ);  // wave-uniform

    const float gamma = fmaxf(tanhf(raw_gamma[0]), EPS);

    // vj[j] = vrow[1 + t0 + j]: shift the aligned pair left by one element,
    // pulling element 8 from the next lane. Lane 63: vrow[512] == vlast.
    const float nx = __shfl_down(v4a.x, 1, 64);
    float vj[TPL] = {v4a.y, v4a.z, v4a.w, v4b.x, v4b.y, v4b.z, v4b.w,
                     (lane == 63) ? vlast : nx};

    float rj[TPL] = {r4a.x, r4a.y, r4a.z, r4a.w, r4b.x, r4b.y, r4b.z, r4b.w};
    float dj[TPL] = {d4a.x, d4a.y, d4a.z, d4a.w, d4b.x, d4b.y, d4b.z, d4b.w};
    const float lr[TPL] = {l4a.x, l4a.y, l4a.z, l4a.w, l4b.x, l4b.y, l4b.z, l4b.w};
    float lm[TPL];
    #pragma unroll
    for (int j = 0; j < TPL; ++j)
        lm[j] = fmaxf(tanhf(lr[j]), EPS);

    // ---- per-lane affine summary (t descending) ----
    float a[TPL], b[TPL];
    float A = 1.f, Bv = 0.f;
    #pragma unroll
    for (int j = TPL - 1; j >= 0; --j) {
        const float g = gamma * (1.f - dj[j]);
        a[j] = g * lm[j];
        b[j] = fmaf(g * (1.f - lm[j]), vj[j], rj[j]);
        Bv = fmaf(a[j], Bv, b[j]);
        A  = a[j] * A;
    }

    // ---- wave-level inclusive suffix scan of (A,B) ----
    #pragma unroll
    for (int dlt = 1; dlt < 64; dlt <<= 1) {
        const float oA = __shfl_down(A, dlt, 64);
        const float oB = __shfl_down(Bv, dlt, 64);
        if (lane + dlt < 64) {                // compose(mine, downstream)
            Bv = fmaf(A, oB, Bv);
            A  = A * oA;
        }
    }
    float EA = __shfl_down(A, 1, 64);
    float EB = __shfl_down(Bv, 1, 64);
    if (lane == 63) { EA = 1.f; EB = 0.f; }

    // ret at this lane's right boundary; values[row][SEQ] is the scan init
    float ret = fmaf(EA, vlast, EB);

    // ---- replay, emit outputs ----
    float o[TPL];
    #pragma unroll
    for (int j = TPL - 1; j >= 0; --j) {
        ret = fmaf(a[j], ret, b[j]);
        o[j] = ret;
    }
    *(float4*)(orow)     = make_float4(o[0], o[1], o[2], o[3]);
    *(float4*)(orow + 4) = make_float4(o[4], o[5], o[6], o[7]);
}

extern "C" void kernel_launch(void* const* d_in, const int* in_sizes, int n_in,
                              void* d_out, int out_size, void* d_ws, size_t ws_size,
                              hipStream_t stream) {
    const float* values    = (const float*)d_in[0];
    const float* rewards   = (const float*)d_in[1];
    const float* dones     = (const float*)d_in[2];
    const float* raw_gamma = (const float*)d_in[3];
    const float* raw_lambd = (const float*)d_in[4];
    float* out = (float*)d_out;

    const int block = 256;                 // 4 waves = 4 rows per block
    const int grid = BATCH / 4;            // 8192 blocks
    glr_wave_scan7<<<grid, block, 0, stream>>>(
        values, rewards, dones, raw_gamma, raw_lambd, out);
}